// Round 6
// baseline (722.650 us; speedup 1.0000x reference)
//
#include <hip/hip_runtime.h>
#include <hip/hip_bf16.h>
#include <math.h>

#define ITEMS 2048
#define SEQ   64
#define DM    128
#define DFF   512
#define ATT_OFF 131072

typedef unsigned short u16;
typedef __attribute__((ext_vector_type(8))) short short8v;
typedef __attribute__((ext_vector_type(4))) float float4v;

#define MFMA16(a,b,c) __builtin_amdgcn_mfma_f32_16x16x32_bf16(a,b,c,0,0,0)

// LDS strides (u16 elements)
#define XST  136   // X/O/Cb/Hb rows: 272B, 16B-aligned
#define QST4 68    // Q4/K4 rows: 136B, 16B-aligned
#define VST4 70    // V4 rows: 140B (scalar access only; good bank spread)
#define PST  76    // P rows

// arena byte offsets
#define XS_B   0          // u16[64][136] 17408
#define Q4_B   17408      // u16[64][68]  8704
#define K4_B   26112      // u16[64][68]  8704
#define V4_B   34816      // u16[64][70]  8960
#define PL_B   43776      // u16[64][76]  9728
#define ZB_B   53504      // u16[8]
#define PF_B   53520      // f32[64]
#define NB_B   53776      // u64
#define CNT_B  53784
#define NA_B   53788
#define ARENA_SZ 53792

// Cb / Hb alias: [64][136] over Q4+K4 (exactly 17408 B)
#define CB_B   Q4_B
// tail aliases (Q4..PL all dead in tail)
#define HC_B   17408
#define QV_B   17920
#define OV_B   18432
#define YV_B   18944
#define Y2_B   19456
#define GW_B   19968
#define WALL_B 20480      // f32[1024]
#define SALL_B 24576      // f32[512]
#define PALL_B 26624      // f32[512]
#define TALL_B 28672      // f32[1024]
#define FF_B   32768      // f32[512]
#define W4P_B  34816      // f32[256]

// ws layout (u16 elements)
#define WQ_O   0
#define WK_O   16384
#define WV_O   32768
#define WO_O   49152
#define UK_O   65536
#define UV_O   81920
#define W1_O   98304     // [512][128]
#define W2_O   163840    // [128][512]
#define UQ_O   229376
#define UO_O   245760
#define WGQ_O  262144
#define WGK_O  278528
#define W3_O   294912    // [512][128]
#define W4_O   360448    // [128][512]
#define WS_TOT 425984

__device__ __forceinline__ u16 f2b(float f){
  union { float f; unsigned u; } v; v.f = f;
  unsigned r = (v.u + 0x7fffu + ((v.u >> 16) & 1u)) >> 16;
  return (u16)r;
}
__device__ __forceinline__ float b2f(u16 h){
  union { unsigned u; float f; } v; v.u = ((unsigned)h) << 16;
  return v.f;
}
__device__ __forceinline__ float wsum(float v){
  #pragma unroll
  for (int off = 1; off < 64; off <<= 1) v += __shfl_xor(v, off);
  return v;
}
__device__ __forceinline__ void ln_vec(float* v, const float* g, const float* b, int lane){
  float v0 = v[lane], v1 = v[lane+64];
  float m  = wsum(v0+v1) * (1.f/128.f);
  float d0 = v0-m, d1 = v1-m;
  float var = wsum(d0*d0+d1*d1) * (1.f/128.f);
  float inv = rsqrtf(var + 1e-5f);
  v[lane]    = d0*inv*g[lane]    + b[lane];
  v[lane+64] = d1*inv*g[lane+64] + b[lane+64];
}
__device__ __forceinline__ float dot128(const u16* __restrict__ wrow, const float* __restrict__ x){
  const short8v* wr = (const short8v*)wrow;
  float a = 0.f;
  #pragma unroll
  for (int c8 = 0; c8 < 16; c8++){
    short8v v = wr[c8];
    #pragma unroll
    for (int q = 0; q < 8; q++) a += b2f((u16)v[q]) * x[c8*8+q];
  }
  return a;
}

__global__ void prep_all(const float* __restrict__ Wq, const float* __restrict__ Wk,
                         const float* __restrict__ Wv, const float* __restrict__ Wo,
                         const float* __restrict__ Uk, const float* __restrict__ Uv,
                         const float* __restrict__ W1, const float* __restrict__ W2,
                         const float* __restrict__ Uq, const float* __restrict__ Uo,
                         const float* __restrict__ Wgq, const float* __restrict__ Wgk,
                         const float* __restrict__ W3, const float* __restrict__ W4,
                         u16* __restrict__ wts){
  int idx = blockIdx.x*256 + threadIdx.x;
  if (idx >= WS_TOT) return;
  float v;
  if (idx < 98304){
    int wsel = idx >> 14, r = idx & 16383;
    const float* tab[6] = {Wq,Wk,Wv,Wo,Uk,Uv};
    int o = r >> 7, i = r & 127;
    v = tab[wsel][i*128 + o];
  } else if (idx < W2_O){
    int r = idx - W1_O; int o = r >> 7, i = r & 127;
    v = W1[i*512 + o];
  } else if (idx < UQ_O){
    int r = idx - W2_O; int o = r >> 9, i = r & 511;
    v = W2[i*128 + o];
  } else if (idx < UO_O){
    int r = idx - UQ_O; int o = r >> 7, i = r & 127;
    v = Uq[i*128 + o];
  } else if (idx < WGQ_O){
    int r = idx - UO_O; int o = r >> 7, i = r & 127;
    v = Uo[i*128 + o];
  } else if (idx < WGK_O){
    int r = idx - WGQ_O; int o = r >> 7, i = r & 127;
    v = Wgq[i*128 + o];
  } else if (idx < W3_O){
    v = Wgk[idx - WGK_O];
  } else if (idx < W4_O){
    int r = idx - W3_O; int j = r >> 7, e = r & 127;
    v = W3[e*512 + j];
  } else {
    int r = idx - W4_O; int o = r >> 9, j = r & 511;
    v = W4[j*128 + o];
  }
  wts[idx] = f2b(v);
}

__global__ void init_avg(float* __restrict__ out){
  out[ATT_OFF + blockIdx.x*256 + threadIdx.x] = 0.f;
}

__global__ __launch_bounds__(256, 4) void vicsek_fused(
    const float* __restrict__ agent_infos,
    const int*   __restrict__ nmask,
    const int*   __restrict__ pmask,
    const u16*   __restrict__ wts,
    const float* __restrict__ W_emb, const float* __restrict__ b_emb,
    const float* __restrict__ ln1g,  const float* __restrict__ ln1b,
    const float* __restrict__ b1,    const float* __restrict__ b2,
    const float* __restrict__ ln2g,  const float* __restrict__ ln2b,
    const float* __restrict__ ln3g,  const float* __restrict__ ln3b,
    const float* __restrict__ b3,    const float* __restrict__ b4,
    const float* __restrict__ ln4g,  const float* __restrict__ ln4b,
    float* __restrict__ out)
{
  __shared__ __align__(16) char arena[ARENA_SZ];
  u16* Xs = (u16*)(arena + XS_B);
  u16* Q4 = (u16*)(arena + Q4_B);
  u16* K4 = (u16*)(arena + K4_B);
  u16* V4 = (u16*)(arena + V4_B);
  u16* Cb = (u16*)(arena + CB_B);
  u16* Pl = (u16*)(arena + PL_B);
  u16* zb = (u16*)(arena + ZB_B);
  float* padf  = (float*)(arena + PF_B);
  float* cnt_s = (float*)(arena + CNT_B);
  float* na_s  = (float*)(arena + NA_B);
  unsigned long long* nb_s = (unsigned long long*)(arena + NB_B);

  const int item = blockIdx.x;
  const int tid  = threadIdx.x;
  const int lane = tid & 63;
  const int w    = tid >> 6;
  const int row0 = w*16;
  const int arow = lane & 15;
  const int akg  = lane >> 4;

  const u16* WqT = wts + WQ_O;  const u16* WkT = wts + WK_O;
  const u16* WvT = wts + WV_O;  const u16* WoT = wts + WO_O;
  const u16* UkT = wts + UK_O;  const u16* UvT = wts + UV_O;
  const u16* W1T = wts + W1_O;  const u16* W2T = wts + W2_O;
  const u16* UqT = wts + UQ_O;  const u16* UoT = wts + UO_O;
  const u16* WgqT = wts + WGQ_O; const u16* WgkB = wts + WGK_O;
  const u16* W3T = wts + W3_O;  const u16* W4T = wts + W4_O;

  // ---- flags ----
  if (w == 0){
    int m = nmask[item*SEQ + lane];
    padf[lane] = m ? 0.f : 1.f;            // reference: pad = ~neigh
    float c = wsum(m ? 1.f : 0.f);
    unsigned long long bb = __ballot(m != 0);
    if (lane == 0){ cnt_s[0] = c; nb_s[0] = bb; }
  }
  if (w == 1){
    float na = wsum((float)pmask[(item>>6)*SEQ + lane]);
    if (lane == 0) na_s[0] = na;
  }
  if (tid < 8) zb[tid] = 0;

  // ---- Stage A: embed ----
  const float* src = agent_infos + (size_t)item*SEQ*6;
  for (int e = tid; e < SEQ*DM; e += 256){
    int r = e >> 7, c = e & 127;
    float a = b_emb[c];
    #pragma unroll
    for (int k = 0; k < 6; k++) a += src[r*6+k]*W_emb[k*DM+c];
    Xs[r*XST + c] = f2b(a);
  }
  __syncthreads();

  const unsigned long long nbits = nb_s[0];

  // residual capture for own output cols (w*32 .. w*32+31), all 64 rows
  float4v accW[2][4];
  #pragma unroll
  for (int tt = 0; tt < 2; tt++)
    #pragma unroll
    for (int rg = 0; rg < 4; rg++)
      #pragma unroll
      for (int i = 0; i < 4; i++)
        accW[tt][rg][i] = b2f(Xs[(rg*16+akg*4+i)*XST + (2*w+tt)*16 + arow]);

  // ---- QKV staging: wave w stages head (4b+w), all 64 rows (col-split, no dup) ----
  auto stage_batch = [&](int b){
    int hh = 4*b + w;
    short8v bq[4], bk[4], bv[4];
    #pragma unroll
    for (int k = 0; k < 4; k++){
      bq[k] = *(const short8v*)(WqT + (hh*16+arow)*128 + k*32 + akg*8);
      bk[k] = *(const short8v*)(WkT + (hh*16+arow)*128 + k*32 + akg*8);
      bv[k] = *(const short8v*)(WvT + (hh*16+arow)*128 + k*32 + akg*8);
    }
    #pragma unroll
    for (int rg = 0; rg < 4; rg++){
      float4v cq = {0,0,0,0}, ck = {0,0,0,0}, cv = {0,0,0,0};
      #pragma unroll
      for (int k = 0; k < 4; k++){
        short8v a = *(const short8v*)(Xs + (rg*16+arow)*XST + k*32 + akg*8);
        cq = MFMA16(a, bq[k], cq);
        ck = MFMA16(a, bk[k], ck);
        cv = MFMA16(a, bv[k], cv);
      }
      #pragma unroll
      for (int i = 0; i < 4; i++){
        int r = rg*16 + akg*4 + i;
        Q4[r*QST4 + w*16 + arow] = f2b(cq[i]);
        K4[r*QST4 + w*16 + arow] = f2b(ck[i]);
        V4[r*VST4 + w*16 + arow] = f2b(cv[i]);
      }
    }
  };

  // ---- attention for 4 staged heads; q = own 16 rows; O kept in regs ----
  auto heads_batch = [&](float4v* ocp){
    #pragma unroll
    for (int l = 0; l < 4; l++){
      const u16* qp = (akg < 2) ? (Q4 + (row0+arow)*QST4 + l*16 + akg*8) : zb;
      short8v bq = *(const short8v*)qp;
      float4v st[4];
      #pragma unroll
      for (int kb = 0; kb < 4; kb++){
        const u16* kp = (akg < 2) ? (K4 + (kb*16+arow)*QST4 + l*16 + akg*8) : zb;
        float4v z = {0,0,0,0};
        st[kb] = MFMA16(*(const short8v*)kp, bq, z);
      }
      bool qok = (nbits >> (row0+arow)) & 1ull;
      float pr[16]; float mx = -3.0e38f;
      #pragma unroll
      for (int kb = 0; kb < 4; kb++)
        #pragma unroll
        for (int i = 0; i < 4; i++){
          int key = kb*16 + akg*4 + i;
          float s = st[kb][i]*0.25f;
          if (!qok || !((nbits>>key)&1ull)) s = -1.0e9f;
          pr[kb*4+i] = s; mx = fmaxf(mx, s);
        }
      mx = fmaxf(mx, __shfl_xor(mx,16)); mx = fmaxf(mx, __shfl_xor(mx,32));
      float sum = 0.f;
      #pragma unroll
      for (int z2 = 0; z2 < 16; z2++){ pr[z2] = __expf(pr[z2]-mx); sum += pr[z2]; }
      sum += __shfl_xor(sum,16); sum += __shfl_xor(sum,32);
      float inv = 1.f/sum;
      #pragma unroll
      for (int kb = 0; kb < 4; kb++)
        #pragma unroll
        for (int i = 0; i < 4; i++)
          Pl[(kb*16+akg*4+i)*PST + row0+arow] = f2b(pr[kb*4+i]*inv);
      // O = P @ V : A = P (own q rows), B = V (normal layout, scalar frag reads)
      float4v o = {0,0,0,0};
      #pragma unroll
      for (int c2 = 0; c2 < 2; c2++){
        short8v pa, bv;
        #pragma unroll
        for (int j = 0; j < 8; j++){
          int key = c2*32 + akg*8 + j;
          pa[j] = (short)Pl[key*PST + row0+arow];
          bv[j] = (short)V4[key*VST4 + l*16 + arow];
        }
        o = MFMA16(pa, bv, o);
      }
      ocp[l] = o;
    }
  };

  float4v ocA[4], ocB[4];
  stage_batch(0);
  __syncthreads();
  heads_batch(ocA);
  __syncthreads();          // batch-0 Q/K/V reads done
  stage_batch(1);           // reads Xs (still X), writes Q4/K4/V4
  __syncthreads();
  // write O batch 0 (heads 0-3) into Xs cols 0..63 (X no longer needed there)
  #pragma unroll
  for (int l = 0; l < 4; l++)
    #pragma unroll
    for (int i = 0; i < 4; i++)
      Xs[(row0+akg*4+i)*XST + l*16 + arow] = f2b(ocA[l][i]);
  heads_batch(ocB);
  #pragma unroll
  for (int l = 0; l < 4; l++)
    #pragma unroll
    for (int i = 0; i < 4; i++)
      Xs[(row0+akg*4+i)*XST + (4+l)*16 + arow] = f2b(ocB[l][i]);
  __syncthreads();          // O complete in Xs

  // ---- Wo projection (col-split) + residual -> Cb ----
  {
    short8v bWo[2][4];
    #pragma unroll
    for (int tt = 0; tt < 2; tt++)
      #pragma unroll
      for (int k = 0; k < 4; k++)
        bWo[tt][k] = *(const short8v*)(WoT + ((2*w+tt)*16+arow)*128 + k*32 + akg*8);
    #pragma unroll
    for (int k = 0; k < 4; k++)
      #pragma unroll
      for (int rg = 0; rg < 4; rg++){
        short8v a = *(const short8v*)(Xs + (rg*16+arow)*XST + k*32 + akg*8);
        #pragma unroll
        for (int tt = 0; tt < 2; tt++)
          accW[tt][rg] = MFMA16(a, bWo[tt][k], accW[tt][rg]);
      }
    #pragma unroll
    for (int tt = 0; tt < 2; tt++)
      #pragma unroll
      for (int rg = 0; rg < 4; rg++)
        #pragma unroll
        for (int i = 0; i < 4; i++)
          Cb[(rg*16+akg*4+i)*XST + (2*w+tt)*16 + arow] = f2b(accW[tt][rg][i]);
  }
  __syncthreads();
  // LN1 row-split: wave w rows row0..row0+15, Cb -> Xs
  for (int rr = 0; rr < 16; rr++){
    int r = row0 + rr;
    float v0 = b2f(Cb[r*XST+lane]), v1 = b2f(Cb[r*XST+lane+64]);
    float m  = wsum(v0+v1) * (1.f/128.f);
    float d0 = v0-m, d1 = v1-m;
    float var = wsum(d0*d0+d1*d1) * (1.f/128.f);
    float inv = rsqrtf(var + 1e-5f);
    Xs[r*XST+lane]    = f2b(d0*inv*ln1g[lane]    + ln1b[lane]);
    Xs[r*XST+lane+64] = f2b(d1*inv*ln1g[lane+64] + ln1b[lane+64]);
  }
  __syncthreads();

  // ---- FFN (col-split, 4 hidden chunks), accY resident ----
  {
    u16* Hb = Cb;
    float4v accY[2][4];
    #pragma unroll
    for (int tt = 0; tt < 2; tt++){
      float bb = b2[(2*w+tt)*16 + arow];
      #pragma unroll
      for (int rg = 0; rg < 4; rg++)
        #pragma unroll
        for (int i = 0; i < 4; i++)
          accY[tt][rg][i] = bb + b2f(Xs[(rg*16+akg*4+i)*XST + (2*w+tt)*16 + arow]);
    }
    for (int c = 0; c < 4; c++){
      short8v bW1[2][4];
      #pragma unroll
      for (int tt = 0; tt < 2; tt++)
        #pragma unroll
        for (int k = 0; k < 4; k++)
          bW1[tt][k] = *(const short8v*)(W1T + (c*128 + w*32 + tt*16 + arow)*128 + k*32 + akg*8);
      float4v hid[2][4];
      #pragma unroll
      for (int tt = 0; tt < 2; tt++){
        float bb = b1[c*128 + w*32 + tt*16 + arow];
        #pragma unroll
        for (int rg = 0; rg < 4; rg++){ hid[tt][rg][0]=bb; hid[tt][rg][1]=bb; hid[tt][rg][2]=bb; hid[tt][rg][3]=bb; }
      }
      #pragma unroll
      for (int k = 0; k < 4; k++)
        #pragma unroll
        for (int rg = 0; rg < 4; rg++){
          short8v a = *(const short8v*)(Xs + (rg*16+arow)*XST + k*32 + akg*8);
          #pragma unroll
          for (int tt = 0; tt < 2; tt++)
            hid[tt][rg] = MFMA16(a, bW1[tt][k], hid[tt][rg]);
        }
      #pragma unroll
      for (int tt = 0; tt < 2; tt++)
        #pragma unroll
        for (int rg = 0; rg < 4; rg++)
          #pragma unroll
          for (int i = 0; i < 4; i++)
            Hb[(rg*16+akg*4+i)*XST + w*32 + tt*16 + arow] = f2b(fmaxf(hid[tt][rg][i], 0.f));
      __syncthreads();
      short8v bW2[2][4];
      #pragma unroll
      for (int tt = 0; tt < 2; tt++)
        #pragma unroll
        for (int k = 0; k < 4; k++)
          bW2[tt][k] = *(const short8v*)(W2T + (w*32 + tt*16 + arow)*512 + c*128 + k*32 + akg*8);
      #pragma unroll
      for (int k = 0; k < 4; k++)
        #pragma unroll
        for (int rg = 0; rg < 4; rg++){
          short8v aH = *(const short8v*)(Hb + (rg*16+arow)*XST + k*32 + akg*8);
          #pragma unroll
          for (int tt = 0; tt < 2; tt++)
            accY[tt][rg] = MFMA16(aH, bW2[tt][k], accY[tt][rg]);
        }
      __syncthreads();   // before next chunk overwrites Hb
    }
    #pragma unroll
    for (int tt = 0; tt < 2; tt++)
      #pragma unroll
      for (int rg = 0; rg < 4; rg++)
        #pragma unroll
        for (int i = 0; i < 4; i++)
          Cb[(rg*16+akg*4+i)*XST + (2*w+tt)*16 + arow] = f2b(accY[tt][rg][i]);
  }
  __syncthreads();
  // LN2 row-split: Cb -> Xs
  for (int rr = 0; rr < 16; rr++){
    int r = row0 + rr;
    float v0 = b2f(Cb[r*XST+lane]), v1 = b2f(Cb[r*XST+lane+64]);
    float m  = wsum(v0+v1) * (1.f/128.f);
    float d0 = v0-m, d1 = v1-m;
    float var = wsum(d0*d0+d1*d1) * (1.f/128.f);
    float inv = rsqrtf(var + 1e-5f);
    Xs[r*XST+lane]    = f2b(d0*inv*ln2g[lane]    + ln2b[lane]);
    Xs[r*XST+lane+64] = f2b(d1*inv*ln2g[lane+64] + ln2b[lane+64]);
  }
  __syncthreads();   // Xs final

  float* hc   = (float*)(arena + HC_B);
  float* qv   = (float*)(arena + QV_B);
  float* ov   = (float*)(arena + OV_B);
  float* yv   = (float*)(arena + YV_B);
  float* y2   = (float*)(arena + Y2_B);
  float* gw   = (float*)(arena + GW_B);
  float* wall = (float*)(arena + WALL_B);
  float* sall = (float*)(arena + SALL_B);
  float* pall = (float*)(arena + PALL_B);
  float* tall = (float*)(arena + TALL_B);
  float* ff   = (float*)(arena + FF_B);
  float* w4p  = (float*)(arena + W4P_B);

  // ---- Stage D: h_c + global average ----
  if (tid < DM){
    float a = 0.f;
    #pragma unroll 8
    for (int r = 0; r < SEQ; r++) a += b2f(Xs[r*XST + tid]) * padf[r];
    a /= cnt_s[0];
    hc[tid] = a;
    atomicAdd(&out[ATT_OFF + (item>>6)*DM + tid], a/na_s[0]);
  }
  __syncthreads();

  // ---- Stage E: cross-attention (1 query), batched over heads ----
  if (tid < DM) qv[tid] = dot128(UqT + tid*128, hc);
  __syncthreads();
  if (tid < DM){
    #pragma unroll
    for (int h = 0; h < 8; h++){
      float a = 0.f;
      #pragma unroll
      for (int d = 0; d < 16; d++) a += b2f(UkT[(h*16+d)*128 + tid]) * qv[h*16+d];
      wall[h*128 + tid] = a;
    }
  }
  __syncthreads();
  for (int idx = tid; idx < 512; idx += 256){
    int h = idx >> 6, j = idx & 63;
    const short8v* xr = (const short8v*)(Xs + j*XST);
    const float* wv_ = wall + h*128;
    float a = 0.f;
    #pragma unroll
    for (int c8 = 0; c8 < 16; c8++){
      short8v v = xr[c8];
      #pragma unroll
      for (int q = 0; q < 8; q++) a += b2f((u16)v[q]) * wv_[c8*8+q];
    }
    sall[idx] = a*0.25f;
  }
  __syncthreads();
  for (int hh = w; hh < 8; hh += 4){
    float s = sall[hh*64 + lane];
    if (!((nbits>>lane)&1ull)) s = -1.0e9f;
    float mxx = s;
    #pragma unroll
    for (int off = 1; off < 64; off <<= 1) mxx = fmaxf(mxx, __shfl_xor(mxx, off));
    float p = __expf(s - mxx);
    float su = wsum(p);
    pall[hh*64 + lane] = p/su;
  }
  __syncthreads();
  {
    int task = tid >> 1, jh = tid & 1;
    int h = task >> 4, c8 = task & 15;
    float acc8[8] = {0,0,0,0,0,0,0,0};
    #pragma unroll 4
    for (int jj = 0; jj < 32; jj++){
      int j = jh*32 + jj;
      short8v v = *(const short8v*)(Xs + j*XST + c8*8);
      float pj = pall[h*64 + j];
      #pragma unroll
      for (int q = 0; q < 8; q++) acc8[q] += pj * b2f((u16)v[q]);
    }
    #pragma unroll
    for (int q = 0; q < 8; q++) acc8[q] += __shfl_xor(acc8[q], 1);
    if (jh == 0){
      #pragma unroll
      for (int q = 0; q < 8; q++) tall[h*128 + c8*8 + q] = acc8[q];
    }
  }
  __syncthreads();
  if (tid < DM) ov[tid] = dot128(UvT + tid*128, tall + (tid>>4)*128);
  __syncthreads();
  if (tid < DM) yv[tid] = hc[tid] + dot128(UoT + tid*128, ov);
  __syncthreads();
  if (w == 0) ln_vec(yv, ln3g, ln3b, lane);
  __syncthreads();

  // ---- Stage F: 1-row FFN + LN4 ----
  for (int j = tid; j < DFF; j += 256)
    ff[j] = fmaxf(b3[j] + dot128(W3T + j*128, yv), 0.f);
  __syncthreads();
  {
    int o = tid & 127, half = tid >> 7;
    const short8v* wr = (const short8v*)(W4T + o*512 + half*256);
    const float* fh = ff + half*256;
    float a = 0.f;
    #pragma unroll
    for (int c8 = 0; c8 < 32; c8++){
      short8v v = wr[c8];
      #pragma unroll
      for (int q = 0; q < 8; q++) a += b2f((u16)v[q]) * fh[c8*8+q];
    }
    w4p[tid] = a;
  }
  __syncthreads();
  if (tid < DM) y2[tid] = b4[tid] + yv[tid] + w4p[tid] + w4p[tid+128];
  __syncthreads();
  if (w == 0) ln_vec(y2, ln4g, ln4b, lane);
  __syncthreads();

  // ---- Stage G: gating ----
  if (tid < DM) qv[tid] = dot128(WgqT + tid*128, y2);
  __syncthreads();
  if (tid < DM) gw[tid] = dot128(WgkB + tid*128, qv);
  __syncthreads();
  if (tid < SEQ){
    float a = dot128(Xs + tid*XST, gw);
    a *= 0.08838834764831845f;   // 1/sqrt(128)
    out[(size_t)item*SEQ + tid] = ((nbits>>tid)&1ull) ? (1.f/(1.f+__expf(-a))) : 0.f;
  }
}

extern "C" void kernel_launch(void* const* d_in, const int* in_sizes, int n_in,
                              void* d_out, int out_size, void* d_ws, size_t ws_size,
                              hipStream_t stream)
{
  const float* agent_infos = (const float*)d_in[0];
  const int*   nmask       = (const int*)  d_in[1];
  const int*   pmask       = (const int*)  d_in[2];
  const float* W_emb = (const float*)d_in[4];
  const float* b_emb = (const float*)d_in[5];
  const float* Wq    = (const float*)d_in[6];
  const float* Wk    = (const float*)d_in[7];
  const float* Wv    = (const float*)d_in[8];
  const float* Wo    = (const float*)d_in[9];
  const float* ln1g  = (const float*)d_in[10];
  const float* ln1b  = (const float*)d_in[11];
  const float* W1    = (const float*)d_in[12];
  const float* b1    = (const float*)d_in[13];
  const float* W2    = (const float*)d_in[14];
  const float* b2    = (const float*)d_in[15];
  const float* ln2g  = (const float*)d_in[16];
  const float* ln2b  = (const float*)d_in[17];
  const float* Uq    = (const float*)d_in[18];
  const float* Uk    = (const float*)d_in[19];
  const float* Uv    = (const float*)d_in[20];
  const float* Uo    = (const float*)d_in[21];
  const float* ln3g  = (const float*)d_in[22];
  const float* ln3b  = (const float*)d_in[23];
  const float* W3    = (const float*)d_in[24];
  const float* b3    = (const float*)d_in[25];
  const float* W4    = (const float*)d_in[26];
  const float* b4    = (const float*)d_in[27];
  const float* ln4g  = (const float*)d_in[28];
  const float* ln4b  = (const float*)d_in[29];
  const float* Wgq   = (const float*)d_in[30];
  const float* Wgk   = (const float*)d_in[31];

  float* out = (float*)d_out;
  u16*   wts = (u16*)d_ws;   // 425984 u16 = 851968 B

  prep_all<<<(WS_TOT+255)/256, 256, 0, stream>>>(Wq, Wk, Wv, Wo, Uk, Uv, W1, W2,
                                                 Uq, Uo, Wgq, Wgk, W3, W4, wts);
  init_avg<<<16, 256, 0, stream>>>(out);
  vicsek_fused<<<ITEMS, 256, 0, stream>>>(
      agent_infos, nmask, pmask, wts, W_emb, b_emb,
      ln1g, ln1b, b1, b2, ln2g, ln2b, ln3g, ln3b,
      b3, b4, ln4g, ln4b, out);
}

// Round 7
// 654.589 us; speedup vs baseline: 1.1040x; 1.1040x over previous
//
#include <hip/hip_runtime.h>
#include <hip/hip_bf16.h>
#include <math.h>

#define ITEMS 2048
#define SEQ   64
#define DM    128
#define DFF   512
#define ATT_OFF 131072

typedef unsigned short u16;
typedef __attribute__((ext_vector_type(4))) unsigned short ushort4v;
typedef __attribute__((ext_vector_type(8))) short short8v;
typedef __attribute__((ext_vector_type(4))) float float4v;

#define MFMA16(a,b,c) __builtin_amdgcn_mfma_f32_16x16x32_bf16(a,b,c,0,0,0)

// LDS strides (u16 elements)
#define XST  136   // X rows: 272B, 16B-aligned
#define QST4 72    // Q4/K4/V4T rows: 144B, 16B-aligned
#define VST4 72
#define PST  68    // P rows (scalar access only)

// arena byte offsets
#define XS_B   0          // u16[64][136] 17408  X -> O -> LN1 -> LN2 (final X)
#define Q4_B   17408      // u16[64][72]  9216   Q, 4-head batch
#define K4_B   26624      // u16[64][72]  9216   K
#define V4_B   35840      // u16[64][72]  9216   V^T (d-rows x key-cols)
#define PL_B   45056      // u16[64][68]  8704   P (same-wave round trip)
#define ZB_B   53760      // u16[8] zero frag
#define PF_B   53776      // f32[64] padf
#define NB_B   54032      // u64
#define CNT_B  54040
#define NA_B   54044
#define ARENA_SZ 54048    // rounds to 54272 -> 3 blocks/CU

// FFN hidden alias over Q4+K4 ([64][136] = 17408 <= 18432)
#define HB_B   Q4_B
// tail aliases (Q4..PL dead in tail)
#define HC_B   17408
#define QV_B   17920
#define OV_B   18432
#define YV_B   18944
#define Y2_B   19456
#define GW_B   19968
#define WALL_B 20480      // f32[1024]
#define SALL_B 24576      // f32[512]
#define PALL_B 26624      // f32[512]
#define TALL_B 28672      // f32[1024]
#define FF_B   35840      // f32[512]  (V4 region)
#define W4P_B  37888      // f32[256]

// ws layout (u16 elements)
#define WQ_O   0
#define WK_O   16384
#define WV_O   32768
#define WO_O   49152
#define UK_O   65536
#define UV_O   81920
#define W1_O   98304     // [512][128]
#define W2_O   163840    // [128][512]
#define UQ_O   229376
#define UO_O   245760
#define WGQ_O  262144
#define WGK_O  278528
#define W3_O   294912    // [512][128]
#define W4_O   360448    // [128][512]
#define WS_TOT 425984

__device__ __forceinline__ u16 f2b(float f){
  union { float f; unsigned u; } v; v.f = f;
  unsigned r = (v.u + 0x7fffu + ((v.u >> 16) & 1u)) >> 16;
  return (u16)r;
}
__device__ __forceinline__ float b2f(u16 h){
  union { unsigned u; float f; } v; v.u = ((unsigned)h) << 16;
  return v.f;
}
__device__ __forceinline__ float wsum(float v){
  #pragma unroll
  for (int off = 1; off < 64; off <<= 1) v += __shfl_xor(v, off);
  return v;
}
__device__ __forceinline__ void ln_vec(float* v, const float* g, const float* b, int lane){
  float v0 = v[lane], v1 = v[lane+64];
  float m  = wsum(v0+v1) * (1.f/128.f);
  float d0 = v0-m, d1 = v1-m;
  float var = wsum(d0*d0+d1*d1) * (1.f/128.f);
  float inv = rsqrtf(var + 1e-5f);
  v[lane]    = d0*inv*g[lane]    + b[lane];
  v[lane+64] = d1*inv*g[lane+64] + b[lane+64];
}
__device__ __forceinline__ float dot128(const u16* __restrict__ wrow, const float* __restrict__ x){
  const short8v* wr = (const short8v*)wrow;
  float a = 0.f;
  #pragma unroll
  for (int c8 = 0; c8 < 16; c8++){
    short8v v = wr[c8];
    #pragma unroll
    for (int q = 0; q < 8; q++) a += b2f((u16)v[q]) * x[c8*8+q];
  }
  return a;
}

__global__ void prep_all(const float* __restrict__ Wq, const float* __restrict__ Wk,
                         const float* __restrict__ Wv, const float* __restrict__ Wo,
                         const float* __restrict__ Uk, const float* __restrict__ Uv,
                         const float* __restrict__ W1, const float* __restrict__ W2,
                         const float* __restrict__ Uq, const float* __restrict__ Uo,
                         const float* __restrict__ Wgq, const float* __restrict__ Wgk,
                         const float* __restrict__ W3, const float* __restrict__ W4,
                         u16* __restrict__ wts){
  int idx = blockIdx.x*256 + threadIdx.x;
  if (idx >= WS_TOT) return;
  float v;
  if (idx < 98304){
    int wsel = idx >> 14, r = idx & 16383;
    const float* tab[6] = {Wq,Wk,Wv,Wo,Uk,Uv};
    int o = r >> 7, i = r & 127;
    v = tab[wsel][i*128 + o];
  } else if (idx < W2_O){
    int r = idx - W1_O; int o = r >> 7, i = r & 127;
    v = W1[i*512 + o];
  } else if (idx < UQ_O){
    int r = idx - W2_O; int o = r >> 9, i = r & 511;
    v = W2[i*128 + o];
  } else if (idx < UO_O){
    int r = idx - UQ_O; int o = r >> 7, i = r & 127;
    v = Uq[i*128 + o];
  } else if (idx < WGQ_O){
    int r = idx - UO_O; int o = r >> 7, i = r & 127;
    v = Uo[i*128 + o];
  } else if (idx < WGK_O){
    int r = idx - WGQ_O; int o = r >> 7, i = r & 127;
    v = Wgq[i*128 + o];
  } else if (idx < W3_O){
    v = Wgk[idx - WGK_O];
  } else if (idx < W4_O){
    int r = idx - W3_O; int j = r >> 7, e = r & 127;
    v = W3[e*512 + j];
  } else {
    int r = idx - W4_O; int o = r >> 9, j = r & 511;
    v = W4[j*128 + o];
  }
  wts[idx] = f2b(v);
}

__global__ void init_avg(float* __restrict__ out){
  out[ATT_OFF + blockIdx.x*256 + threadIdx.x] = 0.f;
}

__global__ __launch_bounds__(256, 3) void vicsek_fused(
    const float* __restrict__ agent_infos,
    const int*   __restrict__ nmask,
    const int*   __restrict__ pmask,
    const u16*   __restrict__ wts,
    const float* __restrict__ W_emb, const float* __restrict__ b_emb,
    const float* __restrict__ ln1g,  const float* __restrict__ ln1b,
    const float* __restrict__ b1,    const float* __restrict__ b2,
    const float* __restrict__ ln2g,  const float* __restrict__ ln2b,
    const float* __restrict__ ln3g,  const float* __restrict__ ln3b,
    const float* __restrict__ b3,    const float* __restrict__ b4,
    const float* __restrict__ ln4g,  const float* __restrict__ ln4b,
    float* __restrict__ out)
{
  __shared__ __align__(16) char arena[ARENA_SZ];
  u16* Xs  = (u16*)(arena + XS_B);
  u16* Q4  = (u16*)(arena + Q4_B);
  u16* K4  = (u16*)(arena + K4_B);
  u16* VT4 = (u16*)(arena + V4_B);
  u16* Pl  = (u16*)(arena + PL_B);
  u16* zb  = (u16*)(arena + ZB_B);
  float* padf  = (float*)(arena + PF_B);
  float* cnt_s = (float*)(arena + CNT_B);
  float* na_s  = (float*)(arena + NA_B);
  unsigned long long* nb_s = (unsigned long long*)(arena + NB_B);

  const int item = blockIdx.x;
  const int tid  = threadIdx.x;
  const int lane = tid & 63;
  const int w    = tid >> 6;
  const int row0 = w*16;
  const int arow = lane & 15;
  const int akg  = lane >> 4;

  const u16* WqT = wts + WQ_O;  const u16* WkT = wts + WK_O;
  const u16* WvT = wts + WV_O;  const u16* WoT = wts + WO_O;
  const u16* UkT = wts + UK_O;  const u16* UvT = wts + UV_O;
  const u16* W1T = wts + W1_O;  const u16* W2T = wts + W2_O;
  const u16* UqT = wts + UQ_O;  const u16* UoT = wts + UO_O;
  const u16* WgqT = wts + WGQ_O; const u16* WgkB = wts + WGK_O;
  const u16* W3T = wts + W3_O;  const u16* W4T = wts + W4_O;

  // ---- flags ----
  if (w == 0){
    int m = nmask[item*SEQ + lane];
    padf[lane] = m ? 0.f : 1.f;            // reference: pad = ~neigh
    float c = wsum(m ? 1.f : 0.f);
    unsigned long long bb = __ballot(m != 0);
    if (lane == 0){ cnt_s[0] = c; nb_s[0] = bb; }
  }
  if (w == 1){
    float na = wsum((float)pmask[(item>>6)*SEQ + lane]);
    if (lane == 0) na_s[0] = na;
  }
  if (tid < 8) zb[tid] = 0;

  // ---- Stage A: embed ----
  const float* src = agent_infos + (size_t)item*SEQ*6;
  for (int e = tid; e < SEQ*DM; e += 256){
    int r = e >> 7, c = e & 127;
    float a = b_emb[c];
    #pragma unroll
    for (int k = 0; k < 6; k++) a += src[r*6+k]*W_emb[k*DM+c];
    Xs[r*XST + c] = f2b(a);
  }
  __syncthreads();

  const unsigned long long nbits = nb_s[0];

  short8v aX[4];
  #pragma unroll
  for (int k = 0; k < 4; k++) aX[k] = *(const short8v*)(Xs + (row0+arow)*XST + k*32 + akg*8);

  // residual preload (Xs will be overwritten by attention O)
  float4v accW[8];
  #pragma unroll
  for (int t = 0; t < 8; t++)
    #pragma unroll
    for (int i = 0; i < 4; i++)
      accW[t][i] = b2f(Xs[(row0+akg*4+i)*XST + t*16 + arow]);

  // ---- stage Q,K (normal) and V^T (swapped) for a 4-head batch (own rows) ----
  auto stage_batch = [&](int b){
    #pragma unroll
    for (int l = 0; l < 4; l++){
      int hh = 4*b + l;
      const u16* wq = WqT + (hh*16+arow)*128 + akg*8;
      const u16* wk = WkT + (hh*16+arow)*128 + akg*8;
      const u16* wv = WvT + (hh*16+arow)*128 + akg*8;
      float4v cq = {0,0,0,0}, ck = {0,0,0,0}, cv = {0,0,0,0};
      #pragma unroll
      for (int k = 0; k < 4; k++){
        cq = MFMA16(aX[k], *(const short8v*)(wq + k*32), cq);
        ck = MFMA16(aX[k], *(const short8v*)(wk + k*32), ck);
        cv = MFMA16(*(const short8v*)(wv + k*32), aX[k], cv);   // V^T[d][key]
      }
      #pragma unroll
      for (int i = 0; i < 4; i++){
        Q4[(row0+akg*4+i)*QST4 + l*16+arow] = f2b(cq[i]);
        K4[(row0+akg*4+i)*QST4 + l*16+arow] = f2b(ck[i]);
        VT4[(l*16+akg*4+i)*VST4 + row0+arow] = f2b(cv[i]);
      }
    }
  };

  // ---- attention for the 4 staged heads; q = own 16 rows; O -> own Xs rows ----
  auto attend_batch = [&](int b){
    #pragma unroll
    for (int l = 0; l < 4; l++){
      const u16* qp = (akg < 2) ? (Q4 + (row0+arow)*QST4 + l*16 + akg*8) : zb;
      short8v bq = *(const short8v*)qp;
      float4v st[4];
      #pragma unroll
      for (int kb = 0; kb < 4; kb++){
        const u16* kp = (akg < 2) ? (K4 + (kb*16+arow)*QST4 + l*16 + akg*8) : zb;
        float4v z = {0,0,0,0};
        st[kb] = MFMA16(*(const short8v*)kp, bq, z);
      }
      bool qok = (nbits >> (row0+arow)) & 1ull;
      float pr[16]; float mx = -3.0e38f;
      #pragma unroll
      for (int kb = 0; kb < 4; kb++)
        #pragma unroll
        for (int i = 0; i < 4; i++){
          int key = kb*16 + akg*4 + i;
          float s = st[kb][i]*0.25f;
          if (!qok || !((nbits>>key)&1ull)) s = -1.0e9f;
          pr[kb*4+i] = s; mx = fmaxf(mx, s);
        }
      mx = fmaxf(mx, __shfl_xor(mx,16)); mx = fmaxf(mx, __shfl_xor(mx,32));
      float sum = 0.f;
      #pragma unroll
      for (int z2 = 0; z2 < 16; z2++){ pr[z2] = __expf(pr[z2]-mx); sum += pr[z2]; }
      sum += __shfl_xor(sum,16); sum += __shfl_xor(sum,32);
      float inv = 1.f/sum;
      #pragma unroll
      for (int kb = 0; kb < 4; kb++)
        #pragma unroll
        for (int i = 0; i < 4; i++)
          Pl[(kb*16+akg*4+i)*PST + row0+arow] = f2b(pr[kb*4+i]*inv);
      // PV: O^T = V^T @ P^T (same-wave LDS round trip)
      float4v ot = {0,0,0,0};
      #pragma unroll
      for (int c2 = 0; c2 < 2; c2++){
        short8v av = *(const short8v*)(VT4 + (l*16+arow)*VST4 + c2*32 + akg*8);
        short8v bp;
        #pragma unroll
        for (int j = 0; j < 8; j++) bp[j] = (short)Pl[(c2*32+akg*8+j)*PST + row0+arow];
        ot = MFMA16(av, bp, ot);
      }
      ushort4v ov4;
      #pragma unroll
      for (int i = 0; i < 4; i++) ov4[i] = f2b(ot[i]);
      *(ushort4v*)(Xs + (row0+arow)*XST + (4*b+l)*16 + akg*4) = ov4;
    }
  };

  stage_batch(0);
  __syncthreads();
  attend_batch(0);
  __syncthreads();          // all reads of batch-0 staging done
  stage_batch(1);
  __syncthreads();
  attend_batch(1);
  __syncthreads();          // staging reads done; Q4/K4 reusable as Hb

  // ---- Wo projection + residual + LN1 (own-wave rows, in-register) ----
  {
    short8v aO[4];
    #pragma unroll
    for (int k = 0; k < 4; k++) aO[k] = *(const short8v*)(Xs + (row0+arow)*XST + k*32 + akg*8);
    #pragma unroll
    for (int k = 0; k < 4; k++)
      #pragma unroll
      for (int t = 0; t < 8; t++)
        accW[t] = MFMA16(aO[k], *(const short8v*)(WoT + (t*16+arow)*128 + k*32 + akg*8), accW[t]);
    float g8[8], bb8[8];
    #pragma unroll
    for (int t = 0; t < 8; t++){ g8[t] = ln1g[t*16+arow]; bb8[t] = ln1b[t*16+arow]; }
    #pragma unroll
    for (int i = 0; i < 4; i++){
      float sm = 0.f;
      #pragma unroll
      for (int t = 0; t < 8; t++) sm += accW[t][i];
      sm += __shfl_xor(sm,1); sm += __shfl_xor(sm,2); sm += __shfl_xor(sm,4); sm += __shfl_xor(sm,8);
      float mean = sm*(1.f/128.f);
      float vs = 0.f;
      #pragma unroll
      for (int t = 0; t < 8; t++){ float d = accW[t][i]-mean; vs += d*d; }
      vs += __shfl_xor(vs,1); vs += __shfl_xor(vs,2); vs += __shfl_xor(vs,4); vs += __shfl_xor(vs,8);
      float inv = rsqrtf(vs*(1.f/128.f) + 1e-5f);
      #pragma unroll
      for (int t = 0; t < 8; t++)
        Xs[(row0+akg*4+i)*XST + t*16 + arow] = f2b((accW[t][i]-mean)*inv*g8[t] + bb8[t]);
    }
  }
  #pragma unroll
  for (int k = 0; k < 4; k++) aX[k] = *(const short8v*)(Xs + (row0+arow)*XST + k*32 + akg*8);

  // ---- FFN (own-wave rows, hidden in Hb alias, no barriers) ----
  {
    u16* Hb = (u16*)(arena + HB_B);
    float4v accY[8];
    #pragma unroll
    for (int t = 0; t < 8; t++){
      float bb = b2[t*16 + arow];
      #pragma unroll
      for (int i = 0; i < 4; i++)
        accY[t][i] = bb + b2f(Xs[(row0+akg*4+i)*XST + t*16 + arow]);
    }
    for (int c = 0; c < 4; c++){
      #pragma unroll
      for (int t = 0; t < 8; t++){
        float bb = b1[c*128 + t*16 + arow];
        float4v acc = {bb,bb,bb,bb};
        #pragma unroll
        for (int k = 0; k < 4; k++)
          acc = MFMA16(aX[k], *(const short8v*)(W1T + (c*128+t*16+arow)*128 + k*32 + akg*8), acc);
        #pragma unroll
        for (int i = 0; i < 4; i++)
          Hb[(row0+akg*4+i)*XST + t*16 + arow] = f2b(fmaxf(acc[i], 0.f));
      }
      #pragma unroll
      for (int k = 0; k < 4; k++){
        short8v aH = *(const short8v*)(Hb + (row0+arow)*XST + k*32 + akg*8);
        #pragma unroll
        for (int t = 0; t < 8; t++)
          accY[t] = MFMA16(aH, *(const short8v*)(W2T + (t*16+arow)*512 + c*128 + k*32 + akg*8), accY[t]);
      }
    }
    float g8[8], bb8[8];
    #pragma unroll
    for (int t = 0; t < 8; t++){ g8[t] = ln2g[t*16+arow]; bb8[t] = ln2b[t*16+arow]; }
    #pragma unroll
    for (int i = 0; i < 4; i++){
      float sm = 0.f;
      #pragma unroll
      for (int t = 0; t < 8; t++) sm += accY[t][i];
      sm += __shfl_xor(sm,1); sm += __shfl_xor(sm,2); sm += __shfl_xor(sm,4); sm += __shfl_xor(sm,8);
      float mean = sm*(1.f/128.f);
      float vs = 0.f;
      #pragma unroll
      for (int t = 0; t < 8; t++){ float d = accY[t][i]-mean; vs += d*d; }
      vs += __shfl_xor(vs,1); vs += __shfl_xor(vs,2); vs += __shfl_xor(vs,4); vs += __shfl_xor(vs,8);
      float inv = rsqrtf(vs*(1.f/128.f) + 1e-5f);
      #pragma unroll
      for (int t = 0; t < 8; t++)
        Xs[(row0+akg*4+i)*XST + t*16 + arow] = f2b((accY[t][i]-mean)*inv*g8[t] + bb8[t]);
    }
  }
  __syncthreads();   // Xs final; staging regions become tail scratch

  float* hc   = (float*)(arena + HC_B);
  float* qv   = (float*)(arena + QV_B);
  float* ov   = (float*)(arena + OV_B);
  float* yv   = (float*)(arena + YV_B);
  float* y2   = (float*)(arena + Y2_B);
  float* gw   = (float*)(arena + GW_B);
  float* wall = (float*)(arena + WALL_B);
  float* sall = (float*)(arena + SALL_B);
  float* pall = (float*)(arena + PALL_B);
  float* tall = (float*)(arena + TALL_B);
  float* ff   = (float*)(arena + FF_B);
  float* w4p  = (float*)(arena + W4P_B);

  // ---- Stage D: h_c + global average ----
  if (tid < DM){
    float a = 0.f;
    #pragma unroll 8
    for (int r = 0; r < SEQ; r++) a += b2f(Xs[r*XST + tid]) * padf[r];
    a /= cnt_s[0];
    hc[tid] = a;
    atomicAdd(&out[ATT_OFF + (item>>6)*DM + tid], a/na_s[0]);
  }
  __syncthreads();

  // ---- Stage E: cross-attention (1 query), batched over heads ----
  if (tid < DM) qv[tid] = dot128(UqT + tid*128, hc);
  __syncthreads();
  if (tid < DM){
    #pragma unroll
    for (int h = 0; h < 8; h++){
      float a = 0.f;
      #pragma unroll
      for (int d = 0; d < 16; d++) a += b2f(UkT[(h*16+d)*128 + tid]) * qv[h*16+d];
      wall[h*128 + tid] = a;
    }
  }
  __syncthreads();
  for (int idx = tid; idx < 512; idx += 256){
    int h = idx >> 6, j = idx & 63;
    const short8v* xr = (const short8v*)(Xs + j*XST);
    const float* wv_ = wall + h*128;
    float a = 0.f;
    #pragma unroll
    for (int c8 = 0; c8 < 16; c8++){
      short8v v = xr[c8];
      #pragma unroll
      for (int q = 0; q < 8; q++) a += b2f((u16)v[q]) * wv_[c8*8+q];
    }
    sall[idx] = a*0.25f;
  }
  __syncthreads();
  for (int hh = w; hh < 8; hh += 4){
    float s = sall[hh*64 + lane];
    if (!((nbits>>lane)&1ull)) s = -1.0e9f;
    float mxx = s;
    #pragma unroll
    for (int off = 1; off < 64; off <<= 1) mxx = fmaxf(mxx, __shfl_xor(mxx, off));
    float p = __expf(s - mxx);
    float su = wsum(p);
    pall[hh*64 + lane] = p/su;
  }
  __syncthreads();
  {
    int task = tid >> 1, jh = tid & 1;
    int h = task >> 4, c8 = task & 15;
    float acc8[8] = {0,0,0,0,0,0,0,0};
    #pragma unroll 4
    for (int jj = 0; jj < 32; jj++){
      int j = jh*32 + jj;
      short8v v = *(const short8v*)(Xs + j*XST + c8*8);
      float pj = pall[h*64 + j];
      #pragma unroll
      for (int q = 0; q < 8; q++) acc8[q] += pj * b2f((u16)v[q]);
    }
    #pragma unroll
    for (int q = 0; q < 8; q++) acc8[q] += __shfl_xor(acc8[q], 1);
    if (jh == 0){
      #pragma unroll
      for (int q = 0; q < 8; q++) tall[h*128 + c8*8 + q] = acc8[q];
    }
  }
  __syncthreads();
  if (tid < DM) ov[tid] = dot128(UvT + tid*128, tall + (tid>>4)*128);
  __syncthreads();
  if (tid < DM) yv[tid] = hc[tid] + dot128(UoT + tid*128, ov);
  __syncthreads();
  if (w == 0) ln_vec(yv, ln3g, ln3b, lane);
  __syncthreads();

  // ---- Stage F: 1-row FFN + LN4 ----
  for (int j = tid; j < DFF; j += 256)
    ff[j] = fmaxf(b3[j] + dot128(W3T + j*128, yv), 0.f);
  __syncthreads();
  {
    int o = tid & 127, half = tid >> 7;
    const short8v* wr = (const short8v*)(W4T + o*512 + half*256);
    const float* fh = ff + half*256;
    float a = 0.f;
    #pragma unroll
    for (int c8 = 0; c8 < 32; c8++){
      short8v v = wr[c8];
      #pragma unroll
      for (int q = 0; q < 8; q++) a += b2f((u16)v[q]) * fh[c8*8+q];
    }
    w4p[tid] = a;
  }
  __syncthreads();
  if (tid < DM) y2[tid] = b4[tid] + yv[tid] + w4p[tid] + w4p[tid+128];
  __syncthreads();
  if (w == 0) ln_vec(y2, ln4g, ln4b, lane);
  __syncthreads();

  // ---- Stage G: gating ----
  if (tid < DM) qv[tid] = dot128(WgqT + tid*128, y2);
  __syncthreads();
  if (tid < DM) gw[tid] = dot128(WgkB + tid*128, qv);
  __syncthreads();
  if (tid < SEQ){
    float a = dot128(Xs + tid*XST, gw);
    a *= 0.08838834764831845f;   // 1/sqrt(128)
    out[(size_t)item*SEQ + tid] = ((nbits>>tid)&1ull) ? (1.f/(1.f+__expf(-a))) : 0.f;
  }
}

extern "C" void kernel_launch(void* const* d_in, const int* in_sizes, int n_in,
                              void* d_out, int out_size, void* d_ws, size_t ws_size,
                              hipStream_t stream)
{
  const float* agent_infos = (const float*)d_in[0];
  const int*   nmask       = (const int*)  d_in[1];
  const int*   pmask       = (const int*)  d_in[2];
  const float* W_emb = (const float*)d_in[4];
  const float* b_emb = (const float*)d_in[5];
  const float* Wq    = (const float*)d_in[6];
  const float* Wk    = (const float*)d_in[7];
  const float* Wv    = (const float*)d_in[8];
  const float* Wo    = (const float*)d_in[9];
  const float* ln1g  = (const float*)d_in[10];
  const float* ln1b  = (const float*)d_in[11];
  const float* W1    = (const float*)d_in[12];
  const float* b1    = (const float*)d_in[13];
  const float* W2    = (const float*)d_in[14];
  const float* b2    = (const float*)d_in[15];
  const float* ln2g  = (const float*)d_in[16];
  const float* ln2b  = (const float*)d_in[17];
  const float* Uq    = (const float*)d_in[18];
  const float* Uk    = (const float*)d_in[19];
  const float* Uv    = (const float*)d_in[20];
  const float* Uo    = (const float*)d_in[21];
  const float* ln3g  = (const float*)d_in[22];
  const float* ln3b  = (const float*)d_in[23];
  const float* W3    = (const float*)d_in[24];
  const float* b3    = (const float*)d_in[25];
  const float* W4    = (const float*)d_in[26];
  const float* b4    = (const float*)d_in[27];
  const float* ln4g  = (const float*)d_in[28];
  const float* ln4b  = (const float*)d_in[29];
  const float* Wgq   = (const float*)d_in[30];
  const float* Wgk   = (const float*)d_in[31];

  float* out = (float*)d_out;
  u16*   wts = (u16*)d_ws;   // 425984 u16 = 851968 B

  prep_all<<<(WS_TOT+255)/256, 256, 0, stream>>>(Wq, Wk, Wv, Wo, Uk, Uv, W1, W2,
                                                 Uq, Uo, Wgq, Wgk, W3, W4, wts);
  init_avg<<<16, 256, 0, stream>>>(out);
  vicsek_fused<<<ITEMS, 256, 0, stream>>>(
      agent_infos, nmask, pmask, wts, W_emb, b_emb,
      ln1g, ln1b, b1, b2, ln2g, ln2b, ln3g, ln3b,
      b3, b4, ln4g, ln4b, out);
}